// Round 2
// baseline (5665.036 us; speedup 1.0000x reference)
//
#include <hip/hip_runtime.h>
#include <hip/hip_bf16.h>
#include <stdint.h>

// ---------------- problem constants ----------------
#define BATCH   128
#define TSTEPS  200
#define NHID    2048
#define PORT    1024
#define NINP    32
#define DT_C    0.042f
#define NWG     128     // one WG per 16 output columns
#define TPB     1024    // 16 waves = ks(0..3) x mg(0..3)

typedef __attribute__((ext_vector_type(8))) short  short8;  // 8 x bf16
typedef __attribute__((ext_vector_type(4))) float  f32x4;

// ---------------- LDS layout ----------------
// BH/BL: [16 cols][KP] bf16 hi/lo of (x2h rows 0..31 ++ h2h rows)/col.
// KP=2088 -> b128 frag reads are <=2-way bank aliased (free).
// L0/L1: 8 KB reduction layers; double as AxH/AxL x-fragment staging.
// Red:   8 KB third layer.
#define KP      2088
#define BL_OFF  (16*KP*2)           // 66816
#define L0_OFF  (2*16*KP*2)         // 133632  (= AxH)
#define L1_OFF  (L0_OFF + 8192)     // 141824  (= AxL)
#define RED_OFF (L1_OFF + 8192)     // 150016
#define SMEM_BYTES (RED_OFF + 8192) // 158208

// ---------------- workspace ----------------
// transport buffer (per parity): 512 blocks (kg*8+mt) x 2048 B = 1 MB.
// block layout: [0,1024): hi frags (lane*16 B), [1024,2048): lo frags.
// element (m,k): block=(k>>5)*8+(m>>4), lane_c=(m&15)+16*((k>>3)&3), sub=k&7.
#define TBUF_BYTES (1u << 20)

__device__ __forceinline__ void grid_barrier(int* cnt, int* gen) {
  __syncthreads();
  if (threadIdx.x == 0) {
    __threadfence();   // release: drain + L2 writeback so transport visible cross-XCD
    int g = __hip_atomic_load(gen, __ATOMIC_RELAXED, __HIP_MEMORY_SCOPE_AGENT);
    int a = __hip_atomic_fetch_add(cnt, 1, __ATOMIC_ACQ_REL, __HIP_MEMORY_SCOPE_AGENT);
    if (a == NWG - 1) {
      __hip_atomic_store(cnt, 0, __ATOMIC_RELAXED, __HIP_MEMORY_SCOPE_AGENT);
      __hip_atomic_store(gen, g + 1, __ATOMIC_RELEASE, __HIP_MEMORY_SCOPE_AGENT);
    } else {
      while (__hip_atomic_load(gen, __ATOMIC_RELAXED, __HIP_MEMORY_SCOPE_AGENT) == g)
        __builtin_amdgcn_s_sleep(1);
    }
    __threadfence();   // acquire: invalidate caches so fresh transport is fetched
  }
  __syncthreads();
}

__device__ __forceinline__ void split2(float v, __hip_bfloat16& h, __hip_bfloat16& l) {
  h = __float2bfloat16(v);
  l = __float2bfloat16(v - __bfloat162float(h));  // residual exact in fp32 (Sterbenz)
}

#define MFMA(a,b,c) __builtin_amdgcn_mfma_f32_16x16x32_bf16((a),(b),(c),0,0,0)

extern "C" __global__ void __launch_bounds__(TPB, 1)
ron_persistent(const float* __restrict__ x,
               const float* __restrict__ x2h,
               const float* __restrict__ h2h,
               const float* __restrict__ gam,
               const float* __restrict__ eps,
               float* __restrict__ out,
               char* __restrict__ ws)
{
  extern __shared__ char smem[];
  __hip_bfloat16* BH  = (__hip_bfloat16*)smem;
  __hip_bfloat16* BL  = (__hip_bfloat16*)(smem + BL_OFF);
  __hip_bfloat16* AxH = (__hip_bfloat16*)(smem + L0_OFF);
  __hip_bfloat16* AxL = (__hip_bfloat16*)(smem + L1_OFF);
  float* L0f = (float*)(smem + L0_OFF);
  float* L1f = (float*)(smem + L1_OFF);
  float* Redf= (float*)(smem + RED_OFF);

  const int tid  = threadIdx.x;
  const int id   = blockIdx.x;
  const int wave = tid >> 6;
  const int lane = tid & 63;
  const int ks   = wave >> 2;       // K segment 0..3 (16 kg each; ks3 also x)
  const int mg   = wave & 3;        // M group -> mtiles {2mg, 2mg+1}
  const int mt0  = mg * 2, mt1 = mg * 2 + 1;
  const int c0   = id * 16;
  const int nl   = lane & 15;       // B col / C col
  const int ql   = lane >> 4;       // quad
  const int colg = c0 + nl;

  __hip_bfloat16* tb0 = (__hip_bfloat16*)ws;
  __hip_bfloat16* tb1 = (__hip_bfloat16*)(ws + TBUF_BYTES);
  int* cnt = (int*)(ws + 2*(size_t)TBUF_BYTES);
  int* gen = cnt + 1;

  // ---- prologue: stage split B (x2h rows 0..31, then h2h) into LDS ----
  for (int i = tid; i < 16*(NHID + NINP); i += TPB) {
    int n = i & 15, k = i >> 4;
    float v = (k < NINP) ? x2h[(size_t)k*NHID + c0 + n]
                         : h2h[(size_t)(k - NINP)*NHID + c0 + n];
    __hip_bfloat16 h, l; split2(v, h, l);
    BH[n*KP + k] = h;  BL[n*KP + k] = l;
  }

  const float gmv = gam[colg];
  const float epv = eps[colg];
  float hy_s[4] = {0.f,0.f,0.f,0.f};   // epilogue waves: rows wave*16+ql*4+r, col colg
  float hz_s[4] = {0.f,0.f,0.f,0.f};

  float* o_hy  = out;
  float* o_hz  = out  + (size_t)TSTEPS*BATCH*NHID;
  float* o_hyu = o_hz + (size_t)TSTEPS*BATCH*PORT;
  float* o_spk = o_hyu+ (size_t)TSTEPS*BATCH*PORT;

  for (int t = 0; t < TSTEPS; ++t) {
    __hip_bfloat16* tcur = (t & 1) ? tb1 : tb0;
    __hip_bfloat16* tnxt = (t & 1) ? tb0 : tb1;

    // ---- phase 0: stage x_t split into A-fragment layout (AxH/AxL) ----
    {
      const int m  = tid >> 3;
      const int k0 = (tid & 7) << 2;
      float4 xv = *(const float4*)(x + ((size_t)m*TSTEPS + t)*NINP + k0);
      const int base = (((m >> 4)*64) + (m & 15) + (((k0 >> 3) & 3) << 4))*8 + (k0 & 7);
      float vs[4] = {xv.x, xv.y, xv.z, xv.w};
      #pragma unroll
      for (int j = 0; j < 4; ++j) {
        __hip_bfloat16 h, l; split2(vs[j], h, l);
        AxH[base + j] = h;  AxL[base + j] = l;
      }
    }
    __syncthreads();   // (also covers prologue B staging on t==0)

    // ---- phase 1: 3-product split-bf16 MFMA over this wave's K range ----
    f32x4 acc0 = {0.f,0.f,0.f,0.f}, acc1 = {0.f,0.f,0.f,0.f};
    if (ks == 3) {  // x contribution (K=32)
      short8 a0h = *(const short8*)(AxH + (mt0*64 + lane)*8);
      short8 a0l = *(const short8*)(AxL + (mt0*64 + lane)*8);
      short8 a1h = *(const short8*)(AxH + (mt1*64 + lane)*8);
      short8 a1l = *(const short8*)(AxL + (mt1*64 + lane)*8);
      short8 bh  = *(const short8*)(BH + nl*KP + ql*8);
      short8 bl  = *(const short8*)(BL + nl*KP + ql*8);
      acc0 = MFMA(a0h, bh, acc0); acc0 = MFMA(a0h, bl, acc0); acc0 = MFMA(a0l, bh, acc0);
      acc1 = MFMA(a1h, bh, acc1); acc1 = MFMA(a1h, bl, acc1); acc1 = MFMA(a1l, bh, acc1);
    }
    {
      const __hip_bfloat16* bhp = BH + nl*KP + NINP + ks*512 + ql*8;
      const __hip_bfloat16* blp = BL + nl*KP + NINP + ks*512 + ql*8;
      const __hip_bfloat16* ap  = tcur + ((size_t)(ks*128 + mt0) << 10) + lane*8;
      #pragma unroll 2
      for (int kgl = 0; kgl < 16; ++kgl) {
        short8 bh = *(const short8*)(bhp + kgl*32);
        short8 bl = *(const short8*)(blp + kgl*32);
        const __hip_bfloat16* a = ap + (size_t)kgl*8192;
        short8 a0h = *(const short8*)(a);
        short8 a0l = *(const short8*)(a + 512);
        short8 a1h = *(const short8*)(a + 1024);
        short8 a1l = *(const short8*)(a + 1536);
        acc0 = MFMA(a0h, bh, acc0);  acc1 = MFMA(a1h, bh, acc1);
        acc0 = MFMA(a0h, bl, acc0);  acc1 = MFMA(a1h, bl, acc1);
        acc0 = MFMA(a0l, bh, acc0);  acc1 = MFMA(a1l, bh, acc1);
      }
    }
    __syncthreads();   // everyone done reading AxH/AxL + B for this step

    // ---- phase 2: reduction round 1 (deterministic tree) ----
    if (ks == 2) { *(f32x4*)(L0f + ((mt0*64 + lane) << 2)) = acc0;
                   *(f32x4*)(L0f + ((mt1*64 + lane) << 2)) = acc1; }
    if (ks == 3) { *(f32x4*)(L1f + ((mt0*64 + lane) << 2)) = acc0;
                   *(f32x4*)(L1f + ((mt1*64 + lane) << 2)) = acc1; }
    __syncthreads();
    if (ks == 0) { f32x4 p0 = *(const f32x4*)(L0f + ((mt0*64 + lane) << 2));
                   f32x4 p1 = *(const f32x4*)(L0f + ((mt1*64 + lane) << 2));
                   acc0 += p0; acc1 += p1; }
    if (ks == 1) { f32x4 p0 = *(const f32x4*)(L1f + ((mt0*64 + lane) << 2));
                   f32x4 p1 = *(const f32x4*)(L1f + ((mt1*64 + lane) << 2));
                   acc0 += p0; acc1 += p1; }
    __syncthreads();
    // ---- phase 4: reduction round 2 -> Red (ks0+ks2), L0 (ks1+ks3) ----
    if (ks == 0) { *(f32x4*)(Redf + ((mt0*64 + lane) << 2)) = acc0;
                   *(f32x4*)(Redf + ((mt1*64 + lane) << 2)) = acc1; }
    if (ks == 1) { *(f32x4*)(L0f  + ((mt0*64 + lane) << 2)) = acc0;
                   *(f32x4*)(L0f  + ((mt1*64 + lane) << 2)) = acc1; }
    __syncthreads();

    // ---- phase 5: epilogue (waves 0..7, one M-tile each) ----
    if (wave < 8) {
      const int mt = wave;
      f32x4 pA = *(const f32x4*)(Redf + ((mt*64 + lane) << 2));
      f32x4 pB = *(const f32x4*)(L0f  + ((mt*64 + lane) << 2));
      const bool harmonic = (c0 < PORT);
      const int kgc = id >> 1;                       // colg>>5, uniform per WG
      const int g2  = ((id & 1) << 1) | ((nl >> 3) & 1);  // (colg>>3)&3
      #pragma unroll
      for (int r = 0; r < 4; ++r) {
        float pre = pA[r] + pB[r];                   // BIAS = 0
        float f = tanhf(pre);
        const int m = mt*16 + ql*4 + r;              // C: row=(lane>>4)*4+r, col=lane&15
        const size_t ob = (size_t)t*BATCH + m;
        float nv;
        if (harmonic) {
          float hz2 = hz_s[r] + DT_C*(f - gmv*hy_s[r] - epv*hz_s[r]);  // old hy
          nv = hy_s[r] + DT_C*hz2;
          hz_s[r] = hz2; hy_s[r] = nv;
          __builtin_nontemporal_store(nv,  &o_hy[ob*NHID + colg]);
          __builtin_nontemporal_store(hz2, &o_hz[ob*PORT + colg]);
        } else {
          float u = hy_s[r];                          // old hy
          float spk = (u > 0.5f) ? 1.0f : 0.0f;
          float u2  = (u > 0.5f) ? 0.0f : u;
          nv = u2 + DT_C*(f - u2);                    // RC = 1
          hy_s[r] = nv;
          __builtin_nontemporal_store(nv,  &o_hy[ob*NHID + colg]);
          __builtin_nontemporal_store(nv,  &o_hyu[ob*PORT + colg - PORT]);
          __builtin_nontemporal_store(spk, &o_spk[ob*PORT + colg - PORT]);
        }
        // split-transport write for next step's A
        __hip_bfloat16 th, tl; split2(nv, th, tl);
        const size_t idx = ((size_t)(kgc*8 + mt) << 10)
                         + (size_t)((ql*4 + r) + (g2 << 4))*8 + (colg & 7);
        tnxt[idx]       = th;
        tnxt[idx + 512] = tl;
      }
    }
    if (t != TSTEPS - 1) grid_barrier(cnt, gen);
  }
}

extern "C" void kernel_launch(void* const* d_in, const int* in_sizes, int n_in,
                              void* d_out, int out_size, void* d_ws, size_t ws_size,
                              hipStream_t stream) {
  const float* x    = (const float*)d_in[0];
  const float* x2h  = (const float*)d_in[1];
  const float* h2h  = (const float*)d_in[2];
  const float* gam  = (const float*)d_in[3];
  const float* eps  = (const float*)d_in[4];

  hipFuncSetAttribute((const void*)ron_persistent,
                      hipFuncAttributeMaxDynamicSharedMemorySize, SMEM_BYTES);
  // zero transport ping/pong (initial hy = 0) + barrier words (ws poisoned 0xAA)
  hipMemsetAsync(d_ws, 0, 2*(size_t)TBUF_BYTES + 64, stream);

  hipLaunchKernelGGL(ron_persistent, dim3(NWG), dim3(TPB), SMEM_BYTES, stream,
                     x, x2h, h2h, gam, eps, (float*)d_out, (char*)d_ws);
}